// Round 1
// baseline (767.215 us; speedup 1.0000x reference)
//
#include <hip/hip_runtime.h>
#include <math.h>

typedef unsigned short u16;
typedef unsigned long long u64;
typedef __attribute__((ext_vector_type(4))) float f32x4;
typedef __attribute__((ext_vector_type(4))) unsigned int u32x4;
typedef __attribute__((ext_vector_type(8))) _Float16 f16x8;

#define NROWS   32768
#define CDIM    512
#define TDIM    768
#define KKEY    128
#define FFDIM   2048
#define NB      8
#define RPB     4096
#define LN_EPS_ 1e-5f
#define TINV    (1.0f/0.07f)
#define RESCUE_MARGIN 1e-5f

__device__ __forceinline__ u16 f2h(float f){ _Float16 h=(_Float16)f; return __builtin_bit_cast(u16,h); }
__device__ __forceinline__ unsigned pk2(float a,float b){ return (unsigned)f2h(a)|((unsigned)f2h(b)<<16); }

__device__ __forceinline__ float wsumf(float v){
#pragma unroll
  for(int o=1;o<64;o<<=1) v+=__shfl_xor(v,o);
  return v; }
__device__ __forceinline__ float wmaxf(float v){
#pragma unroll
  for(int o=1;o<64;o<<=1) v=fmaxf(v,__shfl_xor(v,o));
  return v; }
__device__ __forceinline__ double wsumd(double v){
#pragma unroll
  for(int o=1;o<64;o<<=1) v+=__shfl_xor(v,o);
  return v; }
__device__ __forceinline__ double wmaxd(double v){
#pragma unroll
  for(int o=1;o<64;o<<=1){ double t=__shfl_xor(v,o); v = t>v ? t : v; }
  return v; }

// ---------------------------------------------------------------------------
// Transpose + cast: in (R x C) fp32 -> out (C x R), mode 1 = f16, 0 = fp32
// ---------------------------------------------------------------------------
__global__ __launch_bounds__(256) void transpose_cast_kernel(
    const float* __restrict__ in, void* __restrict__ out, int R, int C, int toF16)
{
  __shared__ float tile[32][33];
  int c0 = blockIdx.x*32, r0 = blockIdx.y*32;
  int tx = threadIdx.x, ty = threadIdx.y;
#pragma unroll
  for (int i=0;i<4;i++){
    int r = r0 + ty + i*8;
    tile[ty+i*8][tx] = in[(size_t)r*C + c0 + tx];
  }
  __syncthreads();
#pragma unroll
  for (int i=0;i<4;i++){
    int cc = c0 + ty + i*8, rr = r0 + tx;
    float v = tile[tx][ty+i*8];
    if (toF16) ((u16*)out)[(size_t)cc*R + rr] = f2h(v);
    else       ((float*)out)[(size_t)cc*R + rr] = v;
  }
}

// ---------------------------------------------------------------------------
// Key stats: per (b,k): normk = max(||text||,1e-12) (fp64 acc), cr = bq.text
// ---------------------------------------------------------------------------
__global__ __launch_bounds__(256) void keystats_kernel(
    const float* __restrict__ text, const float* __restrict__ bq,
    float* __restrict__ normk, float* __restrict__ crr)
{
  int gw = blockIdx.x*4 + (threadIdx.x>>6);   // 0..1023 = b*128+k
  int lane = threadIdx.x & 63;
  const float* tr = &text[(size_t)gw*TDIM];
  double ss=0.0, db=0.0;
#pragma unroll
  for (int i=0;i<12;i++){
    float v = tr[lane + 64*i];
    ss += (double)v*(double)v;
    db += (double)bq[lane+64*i]*(double)v;
  }
  ss = wsumd(ss); db = wsumd(db);
  if (lane==0){
    double nk = sqrt(ss); nk = nk>1e-12 ? nk : 1e-12;
    normk[gw] = (float)nk;
    crr[gw]   = (float)db;
  }
}

// ---------------------------------------------------------------------------
// LN1: vis = LN(residual)*g1+be1 -> vis32 (fp32) and vis16 (f16). wave/row.
// ---------------------------------------------------------------------------
__global__ __launch_bounds__(256) void ln1_kernel(
    const float* __restrict__ visual, const float* __restrict__ g1, const float* __restrict__ be1,
    float* __restrict__ vis32, u16* __restrict__ vis16)
{
  int row = blockIdx.x*4 + (threadIdx.x>>6);
  int lane = threadIdx.x & 63;
  size_t base = (size_t)row*CDIM + lane*8;
  f32x4 a = *(const f32x4*)&visual[base];
  f32x4 c = *(const f32x4*)&visual[base+4];
  float s = a[0]+a[1]+a[2]+a[3]+c[0]+c[1]+c[2]+c[3];
  s = wsumf(s);
  float mu = s * (1.0f/512.0f);
  float q = 0.f;
#pragma unroll
  for (int i=0;i<4;i++){ float d=a[i]-mu; q+=d*d; }
#pragma unroll
  for (int i=0;i<4;i++){ float d=c[i]-mu; q+=d*d; }
  q = wsumf(q);
  float rs = rsqrtf(q*(1.0f/512.0f) + LN_EPS_);
  int cb = lane*8;
  f32x4 o0,o1;
#pragma unroll
  for (int i=0;i<4;i++) o0[i] = (a[i]-mu)*rs*g1[cb+i]   + be1[cb+i];
#pragma unroll
  for (int i=0;i<4;i++) o1[i] = (c[i]-mu)*rs*g1[cb+4+i] + be1[cb+4+i];
  *(f32x4*)&vis32[base]   = o0;
  *(f32x4*)&vis32[base+4] = o1;
  u32x4 hv;
  hv[0]=pk2(o0[0],o0[1]); hv[1]=pk2(o0[2],o0[3]);
  hv[2]=pk2(o1[0],o1[1]); hv[3]=pk2(o1[2],o1[3]);
  *(u32x4*)&vis16[base] = hv;
}

// ---------------------------------------------------------------------------
// Generic fp32 GEMM: C (M x N) = A (M x K) @ Bt(N x K)^T, batched over z.
// 64x64 tile, BK=16, 256 thr, 4x4 per thread.
// ---------------------------------------------------------------------------
__global__ __launch_bounds__(256) void gemm_f32_kernel(
    const float* __restrict__ A, const float* __restrict__ Bt, float* __restrict__ C,
    int M, int N, int K, long sA, long sB, long sC)
{
  __shared__ float As[64][17];
  __shared__ float Bs[64][17];
  const int z = blockIdx.z;
  A  += (size_t)z * sA; Bt += (size_t)z * sB; C += (size_t)z * sC;
  const int tid = threadIdx.x;
  const int tx = tid & 15, ty = tid >> 4;
  const int m0 = blockIdx.x*64, n0 = blockIdx.y*64;
  float acc[4][4];
#pragma unroll
  for (int i=0;i<4;i++)
#pragma unroll
    for (int j=0;j<4;j++) acc[i][j]=0.f;
  const int lr = tid >> 2, lc = (tid & 3)*4;
  for (int k0=0; k0<K; k0+=16){
    f32x4 av = *(const f32x4*)&A [(size_t)(m0+lr)*K + k0 + lc];
    f32x4 bv = *(const f32x4*)&Bt[(size_t)(n0+lr)*K + k0 + lc];
#pragma unroll
    for (int i=0;i<4;i++){ As[lr][lc+i]=av[i]; Bs[lr][lc+i]=bv[i]; }
    __syncthreads();
#pragma unroll
    for (int kk=0; kk<16; kk++){
      float a[4], b[4];
#pragma unroll
      for (int i=0;i<4;i++){ a[i]=As[ty*4+i][kk]; b[i]=Bs[tx*4+i][kk]; }
#pragma unroll
      for (int i=0;i<4;i++)
#pragma unroll
        for (int j=0;j<4;j++) acc[i][j] = fmaf(a[i], b[j], acc[i][j]);
    }
    __syncthreads();
  }
#pragma unroll
  for (int i=0;i<4;i++){
    f32x4 o;
#pragma unroll
    for (int j=0;j<4;j++) o[j]=acc[i][j];
    *(f32x4*)&C[(size_t)(m0+ty*4+i)*N + n0 + tx*4] = o;
  }
}

// ---------------------------------------------------------------------------
// f16 MFMA GEMM: A (M x K), Bt (N x K), both f16, fp32 accum.
// 128x128 tile, BK=64, 4 waves (2x2), 4x4 frags of 16x16x32.
// EPI 0: row sum-of-squares of (acc+bias) -> qpart[row][blockIdx.y*2+wc]
// EPI 1: gelu(acc+bias) -> f16 out_h
// EPI 2: acc + bias + add_f -> fp32 out_f
// ---------------------------------------------------------------------------
__device__ __forceinline__ float gelu_exact(float v){
  return 0.5f*v*(1.0f + erff(v*0.70710678118654752440f));
}

template<int EPI>
__global__ __launch_bounds__(256) void gemm_f16_kernel(
    const u16* __restrict__ A, const u16* __restrict__ Bt,
    int M, int N, int K,
    const float* __restrict__ bias,
    float* __restrict__ out_f,
    u16* __restrict__ out_h,
    const float* __restrict__ add_f)
{
  __shared__ __align__(16) u16 As[128*64];
  __shared__ __align__(16) u16 Bs[128*64];
  const int tid = threadIdx.x;
  const int lane = tid & 63, w = tid >> 6;
  const int wr = w >> 1, wc = w & 1;
  const int m0 = blockIdx.x*128, n0 = blockIdx.y*128;
  f32x4 acc[4][4];
#pragma unroll
  for (int i=0;i<4;i++)
#pragma unroll
    for (int j=0;j<4;j++) acc[i][j] = (f32x4)0.f;
  const int lr = lane & 15, lk = (lane >> 4)*8;
  for (int k0=0; k0<K; k0+=64){
#pragma unroll
    for (int i=0;i<4;i++){
      int ci = tid + i*256;
      int r = ci >> 3, c8 = (ci & 7)*8;
      *(u32x4*)&As[r*64 + c8] = *(const u32x4*)&A [(size_t)(m0+r)*K + k0 + c8];
      *(u32x4*)&Bs[r*64 + c8] = *(const u32x4*)&Bt[(size_t)(n0+r)*K + k0 + c8];
    }
    __syncthreads();
#pragma unroll
    for (int kk=0; kk<64; kk+=32){
      f16x8 af[4], bfv[4];
#pragma unroll
      for (int mi=0;mi<4;mi++) af[mi]  = *(const f16x8*)&As[(wr*64 + mi*16 + lr)*64 + kk + lk];
#pragma unroll
      for (int ni=0;ni<4;ni++) bfv[ni] = *(const f16x8*)&Bs[(wc*64 + ni*16 + lr)*64 + kk + lk];
#pragma unroll
      for (int mi=0;mi<4;mi++)
#pragma unroll
        for (int ni=0;ni<4;ni++)
          acc[mi][ni] = __builtin_amdgcn_mfma_f32_16x16x32_f16(af[mi], bfv[ni], acc[mi][ni], 0, 0, 0);
    }
    __syncthreads();
  }
  const int lr4 = (lane >> 4)*4;
  if (EPI == 0){
    float sq[4][4];
#pragma unroll
    for (int mi=0;mi<4;mi++)
#pragma unroll
      for (int r=0;r<4;r++) sq[mi][r]=0.f;
#pragma unroll
    for (int ni=0;ni<4;ni++){
      float bqv = bias[n0 + wc*64 + ni*16 + lr];
#pragma unroll
      for (int mi=0;mi<4;mi++)
#pragma unroll
        for (int r=0;r<4;r++){
          float v = acc[mi][ni][r] + bqv;
          sq[mi][r] += v*v;
        }
    }
#pragma unroll
    for (int o=1;o<16;o<<=1)
#pragma unroll
      for (int mi=0;mi<4;mi++)
#pragma unroll
        for (int r=0;r<4;r++) sq[mi][r] += __shfl_xor(sq[mi][r], o);
    if ((lane & 15) == 0){
      int part = blockIdx.y*2 + wc;
#pragma unroll
      for (int mi=0;mi<4;mi++)
#pragma unroll
        for (int r=0;r<4;r++){
          int row = m0 + wr*64 + mi*16 + lr4 + r;
          out_f[(size_t)row*12 + part] = sq[mi][r];
        }
    }
  } else {
#pragma unroll
    for (int mi=0;mi<4;mi++)
#pragma unroll
      for (int ni=0;ni<4;ni++){
        int row = m0 + wr*64 + mi*16 + lr4;
        int col = n0 + wc*64 + ni*16 + lr;
        float bb = bias[col];
#pragma unroll
        for (int r=0;r<4;r++){
          float v = acc[mi][ni][r] + bb;
          size_t idx = (size_t)(row+r)*N + col;
          if (EPI == 1) out_h[idx] = f2h(gelu_exact(v));
          else          out_f[idx] = v + add_f[idx];
        }
      }
  }
}

// ---------------------------------------------------------------------------
// fp64 rescue: full recompute of one row (LN1, q, sims, top5, softmax, PV,
// fused, LN2) when the top-5 boundary is ambiguous. Wave-scope.
// ---------------------------------------------------------------------------
__device__ void rescue_row(int row, int b, int lane,
    double* vis64, double* q64,
    const float* __restrict__ visual, const float* __restrict__ text,
    const float* __restrict__ Wq, const float* __restrict__ bq,
    const float* __restrict__ g1, const float* __restrict__ be1,
    const float* __restrict__ g2, const float* __restrict__ be2,
    const float* __restrict__ value, const float* __restrict__ bv,
    float* __restrict__ fusedln32, u16* __restrict__ fused16)
{
  const size_t rb = (size_t)row*CDIM + lane*8;
  double x[8];
#pragma unroll
  for (int j=0;j<8;j++) x[j] = (double)visual[rb + j];
  double s=0.0;
#pragma unroll
  for (int j=0;j<8;j++) s += x[j];
  s = wsumd(s);
  double mu = s*(1.0/512.0);
  double s2=0.0;
#pragma unroll
  for (int j=0;j<8;j++){ double d=x[j]-mu; s2+=d*d; }
  s2 = wsumd(s2);
  double rs = 1.0/sqrt(s2*(1.0/512.0) + 1e-5);
#pragma unroll
  for (int j=0;j<8;j++){
    int c = lane*8+j;
    vis64[c] = (x[j]-mu)*rs*(double)g1[c] + (double)be1[c];
  }
  __builtin_amdgcn_wave_barrier();
  // q = vis@Wq + bq (fp64)
  double qa[12];
#pragma unroll
  for (int i=0;i<12;i++) qa[i] = (double)bq[lane + 64*i];
  for (int c=0;c<CDIM;c++){
    double v = vis64[c];
    const float* wrow = &Wq[(size_t)c*TDIM + lane];
#pragma unroll
    for (int i=0;i<12;i++) qa[i] += v*(double)wrow[64*i];
  }
  double nq2 = 0.0;
#pragma unroll
  for (int i=0;i<12;i++){ q64[lane+64*i] = qa[i]; nq2 += qa[i]*qa[i]; }
  nq2 = wsumd(nq2);
  double nq = sqrt(nq2); nq = nq>1e-12 ? nq : 1e-12;
  __builtin_amdgcn_wave_barrier();
  // sims (2 keys per lane)
  double sv[2];
#pragma unroll
  for (int h2=0; h2<2; ++h2){
    int k = lane + 64*h2;
    const float* trow = &text[((size_t)b*KKEY + k)*TDIM];
    double dot=0.0, nk2=0.0;
    for (int jj=0;jj<TDIM;jj++){
      double tv = (double)trow[jj];
      dot += q64[jj]*tv; nk2 += tv*tv;
    }
    double nk = sqrt(nk2); nk = nk>1e-12 ? nk : 1e-12;
    sv[h2] = dot/(nq*nk);
  }
  // top-5 threshold (counting duplicates)
  double v0=sv[0], v1=sv[1]; bool rm0=false, rm1=false;
  double thr=0.0, smax=0.0;
  for (int it=0; it<5; ++it){
    double c0 = rm0 ? -1e300 : v0;
    double c1 = rm1 ? -1e300 : v1;
    double m = c0>c1 ? c0 : c1;
    m = wmaxd(m);
    if (it==0) smax = m;
    thr = m;
    bool h0 = (!rm0) && (v0==m);
    u64 k0 = __ballot(h0);
    if (k0){ if (lane == __ffsll(k0)-1) rm0 = true; }
    else {
      bool h1 = (!rm1) && (v1==m);
      u64 k1 = __ballot(h1);
      if (lane == __ffsll(k1)-1) rm1 = true;
    }
  }
  double p0 = (v0>=thr) ? exp((v0-smax)*(1.0/0.07)) : 0.0;
  double p1 = (v1>=thr) ? exp((v1-smax)*(1.0/0.07)) : 0.0;
  double Z = wsumd(p0+p1);
  double zi = 1.0/Z;
  double accv[8];
#pragma unroll
  for (int j=0;j<8;j++) accv[j] = (double)bv[lane*8+j];
  u64 mk0 = __ballot(p0>0.0);
  u64 mk1 = __ballot(p1>0.0);
  while (mk0){
    int l = __ffsll(mk0)-1; mk0 &= mk0-1;
    double wt = __shfl(p0, l)*zi;
    const float* vr = &value[((size_t)b*KKEY + l)*CDIM + lane*8];
#pragma unroll
    for (int j=0;j<8;j++) accv[j] += wt*(double)vr[j];
  }
  while (mk1){
    int l = __ffsll(mk1)-1; mk1 &= mk1-1;
    double wt = __shfl(p1, l)*zi;
    const float* vr = &value[((size_t)b*KKEY + l + 64)*CDIM + lane*8];
#pragma unroll
    for (int j=0;j<8;j++) accv[j] += wt*(double)vr[j];
  }
  // fused + LN2 (fp64)
  double f[8];
#pragma unroll
  for (int j=0;j<8;j++) f[j] = (double)visual[rb+j] + accv[j];
  double fs=0.0;
#pragma unroll
  for (int j=0;j<8;j++) fs += f[j];
  fs = wsumd(fs);
  double fmu = fs*(1.0/512.0);
  double fv=0.0;
#pragma unroll
  for (int j=0;j<8;j++){ double d=f[j]-fmu; fv+=d*d; }
  fv = wsumd(fv);
  double frs = 1.0/sqrt(fv*(1.0/512.0) + 1e-5);
#pragma unroll
  for (int j=0;j<8;j++){
    int c = lane*8+j;
    double y = (f[j]-fmu)*frs*(double)g2[c] + (double)be2[c];
    fusedln32[rb+j] = (float)y;
    fused16[rb+j]   = f2h((float)y);
  }
}

// ---------------------------------------------------------------------------
// Attention + residual + LN2: one wave per row.
// ---------------------------------------------------------------------------
__global__ __launch_bounds__(256) void attn_ln2_kernel(
    const float* __restrict__ visual, const float* __restrict__ text,
    const float* __restrict__ tbuf, const float* __restrict__ crr,
    const float* __restrict__ normk, const float* __restrict__ qpart,
    const float* __restrict__ value, const float* __restrict__ bv,
    const float* __restrict__ Wq, const float* __restrict__ bq,
    const float* __restrict__ g1, const float* __restrict__ be1,
    const float* __restrict__ g2, const float* __restrict__ be2,
    float* __restrict__ fusedln32, u16* __restrict__ fused16)
{
  __shared__ double shd[4][1280];   // per wave: vis64[512] + q64[768]
  const int w = threadIdx.x >> 6, lane = threadIdx.x & 63;
  const int row = blockIdx.x*4 + w;
  const int b = row >> 12;
  // ||q||
  float nqp = (lane < 12) ? qpart[(size_t)row*12 + lane] : 0.f;
  float nq2 = wsumf(nqp);
  float nq = fmaxf(sqrtf(nq2), 1e-12f);
  // sims (2 keys per lane)
  const float* trow = &tbuf[(size_t)row*KKEY];
  float s0 = (trow[lane]    + crr[b*KKEY + lane])    / (nq*normk[b*KKEY + lane]);
  float s1 = (trow[lane+64] + crr[b*KKEY + lane+64]) / (nq*normk[b*KKEY + lane+64]);
  // top5 + 6th
  float v0=s0, v1=s1; bool rm0=false, rm1=false;
  float thr=0.f, smax=0.f, m6=0.f;
  for (int it=0; it<6; ++it){
    float c0 = rm0 ? -1e30f : v0;
    float c1 = rm1 ? -1e30f : v1;
    float m = wmaxf(fmaxf(c0,c1));
    if (it==0) smax = m;
    if (it<5){
      thr = m;
      bool h0 = (!rm0) && (v0==m);
      u64 k0 = __ballot(h0);
      if (k0){ if (lane == __ffsll(k0)-1) rm0 = true; }
      else {
        bool h1 = (!rm1) && (v1==m);
        u64 k1 = __ballot(h1);
        if (lane == __ffsll(k1)-1) rm1 = true;
      }
    } else m6 = m;
  }
  if ((thr - m6) < RESCUE_MARGIN){
    rescue_row(row, b, lane, shd[w], shd[w]+512,
               visual, text, Wq, bq, g1, be1, g2, be2, value, bv,
               fusedln32, fused16);
    return;
  }
  float p0 = (s0>=thr) ? expf((s0-smax)*TINV) : 0.f;
  float p1 = (s1>=thr) ? expf((s1-smax)*TINV) : 0.f;
  float Z = wsumf(p0+p1);
  float zi = 1.f/Z;
  float accv[8];
#pragma unroll
  for (int j=0;j<8;j++) accv[j] = bv[lane*8+j];
  u64 mk0 = __ballot(p0>0.f);
  u64 mk1 = __ballot(p1>0.f);
  while (mk0){
    int l = __ffsll(mk0)-1; mk0 &= mk0-1;
    float wt = __shfl(p0, l)*zi;
    const f32x4* vr = (const f32x4*)&value[((size_t)b*KKEY + l)*CDIM + lane*8];
    f32x4 va = vr[0], vb = vr[1];
#pragma unroll
    for (int j=0;j<4;j++){ accv[j] += wt*va[j]; accv[4+j] += wt*vb[j]; }
  }
  while (mk1){
    int l = __ffsll(mk1)-1; mk1 &= mk1-1;
    float wt = __shfl(p1, l)*zi;
    const f32x4* vr = (const f32x4*)&value[((size_t)b*KKEY + l + 64)*CDIM + lane*8];
    f32x4 va = vr[0], vb = vr[1];
#pragma unroll
    for (int j=0;j<4;j++){ accv[j] += wt*va[j]; accv[4+j] += wt*vb[j]; }
  }
  // fused + LN2 (fp32)
  size_t rb = (size_t)row*CDIM + lane*8;
  f32x4 r0v = *(const f32x4*)&visual[rb];
  f32x4 r1v = *(const f32x4*)&visual[rb+4];
  float f[8];
#pragma unroll
  for (int j=0;j<4;j++){ f[j]=r0v[j]+accv[j]; f[4+j]=r1v[j]+accv[4+j]; }
  float fs=0.f;
#pragma unroll
  for (int j=0;j<8;j++) fs += f[j];
  fs = wsumf(fs);
  float fmu = fs*(1.0f/512.0f);
  float fvv=0.f;
#pragma unroll
  for (int j=0;j<8;j++){ float d=f[j]-fmu; fvv+=d*d; }
  fvv = wsumf(fvv);
  float frs = rsqrtf(fvv*(1.0f/512.0f) + LN_EPS_);
  int cb = lane*8;
  f32x4 o0,o1;
#pragma unroll
  for (int j=0;j<4;j++) o0[j] = (f[j]-fmu)*frs*g2[cb+j]     + be2[cb+j];
#pragma unroll
  for (int j=0;j<4;j++) o1[j] = (f[4+j]-fmu)*frs*g2[cb+4+j] + be2[cb+4+j];
  *(f32x4*)&fusedln32[rb]   = o0;
  *(f32x4*)&fusedln32[rb+4] = o1;
  u32x4 hv;
  hv[0]=pk2(o0[0],o0[1]); hv[1]=pk2(o0[2],o0[3]);
  hv[2]=pk2(o1[0],o1[1]); hv[3]=pk2(o1[2],o1[3]);
  *(u32x4*)&fused16[rb] = hv;
}

// ---------------------------------------------------------------------------
extern "C" void kernel_launch(void* const* d_in, const int* in_sizes, int n_in,
                              void* d_out, int out_size, void* d_ws, size_t ws_size,
                              hipStream_t stream)
{
  (void)in_sizes; (void)n_in; (void)out_size; (void)ws_size;
  const float* visual = (const float*)d_in[0];
  const float* text   = (const float*)d_in[1];
  const float* Wq     = (const float*)d_in[2];
  const float* bq     = (const float*)d_in[3];
  const float* Wv     = (const float*)d_in[4];
  const float* bv     = (const float*)d_in[5];
  const float* W1     = (const float*)d_in[6];
  const float* b1     = (const float*)d_in[7];
  const float* W2     = (const float*)d_in[8];
  const float* b2     = (const float*)d_in[9];
  const float* g1     = (const float*)d_in[10];
  const float* be1    = (const float*)d_in[11];
  const float* g2     = (const float*)d_in[12];
  const float* be2    = (const float*)d_in[13];
  float* out = (float*)d_out;

  char* ws = (char*)d_ws;
  size_t off = 0;
  auto alloc = [&](size_t bytes)->char*{
    char* p = ws + off; off += (bytes + 255) & ~(size_t)255; return p; };

  float* vis32  = (float*)alloc((size_t)NROWS*CDIM*4);
  u16*   vis16  = (u16*)  alloc((size_t)NROWS*CDIM*2);
  u16*   h16    = (u16*)  alloc((size_t)NROWS*FFDIM*2);
  float* tbuf   = (float*)alloc((size_t)NROWS*KKEY*4);
  float* Mrt    = (float*)alloc((size_t)NB*KKEY*CDIM*4);
  float* value  = (float*)alloc((size_t)NB*KKEY*CDIM*4);
  u16*   Wq16t  = (u16*)  alloc((size_t)TDIM*CDIM*2);
  u16*   W116t  = (u16*)  alloc((size_t)FFDIM*CDIM*2);
  u16*   W216t  = (u16*)  alloc((size_t)CDIM*FFDIM*2);
  float* WvT    = (float*)alloc((size_t)CDIM*TDIM*4);
  float* qpart  = (float*)alloc((size_t)NROWS*12*4);
  float* normk  = (float*)alloc((size_t)NB*KKEY*4);
  float* crr    = (float*)alloc((size_t)NB*KKEY*4);
  float* fusedln32 = vis32;   // alias: vis32 dead after t-GEMM
  u16*   fused16   = vis16;   // alias: vis16 dead after Qnorm GEMM

  dim3 tb(32,8);
  // weight transposes/casts
  transpose_cast_kernel<<<dim3(TDIM/32,  CDIM/32),  tb, 0, stream>>>(Wq, Wq16t, CDIM, TDIM, 1);
  transpose_cast_kernel<<<dim3(FFDIM/32, CDIM/32),  tb, 0, stream>>>(W1, W116t, CDIM, FFDIM, 1);
  transpose_cast_kernel<<<dim3(CDIM/32,  FFDIM/32), tb, 0, stream>>>(W2, W216t, FFDIM, CDIM, 1);
  transpose_cast_kernel<<<dim3(CDIM/32,  TDIM/32),  tb, 0, stream>>>(Wv, WvT,  TDIM, CDIM, 0);
  // key stats
  keystats_kernel<<<256, 256, 0, stream>>>(text, bq, normk, crr);
  // Mrt[b] (128 x 512) = text[b] (128x768) @ Wq(512x768)^T
  gemm_f32_kernel<<<dim3(2, 8, 8), 256, 0, stream>>>(
      text, Wq, Mrt, KKEY, CDIM, TDIM, (long)KKEY*TDIM, 0, (long)KKEY*CDIM);
  // value[b] (128 x 512) = text[b] @ WvT^T
  gemm_f32_kernel<<<dim3(2, 8, 8), 256, 0, stream>>>(
      text, WvT, value, KKEY, CDIM, TDIM, (long)KKEY*TDIM, 0, (long)KKEY*CDIM);
  // LN1
  ln1_kernel<<<NROWS/4, 256, 0, stream>>>(visual, g1, be1, vis32, vis16);
  // t[b] (4096 x 128) = vis32[b] @ Mrt[b]^T
  gemm_f32_kernel<<<dim3(64, 2, 8), 256, 0, stream>>>(
      vis32, Mrt, tbuf, RPB, KKEY, CDIM, (long)RPB*CDIM, (long)KKEY*CDIM, (long)RPB*KKEY);
  // ||q||^2 partials (f16 MFMA)
  gemm_f16_kernel<0><<<dim3(NROWS/128, TDIM/128), 256, 0, stream>>>(
      vis16, Wq16t, NROWS, TDIM, CDIM, bq, qpart, nullptr, nullptr);
  // attention + residual + LN2 (+ fp64 rescue)
  attn_ln2_kernel<<<NROWS/4, 256, 0, stream>>>(
      visual, text, tbuf, crr, normk, qpart, value, bv,
      Wq, bq, g1, be1, g2, be2, fusedln32, fused16);
  // FFN1: h = gelu(fused @ W1 + b1)
  gemm_f16_kernel<1><<<dim3(NROWS/128, FFDIM/128), 256, 0, stream>>>(
      fused16, W116t, NROWS, FFDIM, CDIM, b1, nullptr, h16, nullptr);
  // FFN2: out = fused_ln + h @ W2 + b2
  gemm_f16_kernel<2><<<dim3(NROWS/128, CDIM/128), 256, 0, stream>>>(
      h16, W216t, NROWS, CDIM, FFDIM, b2, out, nullptr, fusedln32);
}